// Round 20
// baseline (139.731 us; speedup 1.0000x reference)
//
#include <hip/hip_runtime.h>

#define BN 262144
#define HALF (BN / 2)
#define LNUM 15
// per stage (72 floats): SMEM part = [bias 8][rows0-2 24] (32), LDS part = rows3-7 (40)
// stage lin = l*10 + net*5 + st; stage 150 = dup of stage 0 (prefetch overrun pad)
#define NSTG 151
#define NL4 (NSTG * 10)          // LDS slab in f4 (40 floats/stage)
#define NLF (NSTG * 40)
#define NSF (NSTG * 32)
#define LOG2E 1.4426950408889634f
#define LN2 0.6931471805599453f
#define L2CLIP 7.2134752044448170f   // 5*log2e

typedef __attribute__((ext_vector_type(4))) float f4;

__device__ __forceinline__ float raw_val(
    const float* Wi, const float* bi, const float* Wh, const float* bh,
    const float* Wo, const float* bo, int sl, int k /*0..71: [bias8][W64]*/) {
    const int l = sl / 10, r = sl % 10, net = r / 5, st = r % 5;
    const int nb = l * 2 + net;
    const float sc = (net == 0 && st == 4) ? LOG2E : 1.0f;   // log2-domain fold
    if (k < 8) {
        if (st == 0)      return bi[nb * 8 + k];
        else if (st < 4)  return bh[(nb * 3 + (st - 1)) * 8 + k];
        else              return bo[nb * 8 + k] * sc;
    } else {
        const int kk = k - 8;
        if (st == 0)      return Wi[nb * 64 + kk];
        else if (st < 4)  return Wh[(nb * 3 + (st - 1)) * 64 + kk];
        else              return Wo[nb * 64 + kk] * sc;
    }
}

extern "C" __global__ void build_slab(
    const float* __restrict__ Wi, const float* __restrict__ bi,
    const float* __restrict__ Wh, const float* __restrict__ bh,
    const float* __restrict__ Wo, const float* __restrict__ bo,
    float* __restrict__ ws) {
    int idx = blockIdx.x * 256 + threadIdx.x;
    if (idx >= NLF + NSF) return;
    if (idx < NLF) {                 // LDS region: rows 3..7 -> raw k = 32 + j
        int sl = idx / 40, j = idx % 40;
        if (sl == NSTG - 1) sl = 0;
        ws[idx] = raw_val(Wi, bi, Wh, bh, Wo, bo, sl, 32 + j);
    } else {                         // SMEM region: bias + rows 0..2 -> raw k = j
        const int q = idx - NLF;
        int sl = q / 32, j = q % 32;
        if (sl == NSTG - 1) sl = 0;
        ws[idx] = raw_val(Wi, bi, Wh, bh, Wo, bo, sl, j);
    }
}

extern "C" __global__ void compose_perms(const int* __restrict__ perms, int* __restrict__ c) {
    if (threadIdx.x != 0 || blockIdx.x != 0) return;
    int cur[16];
    for (int j = 0; j < 16; ++j) { cur[j] = j; c[j] = j; }
    for (int l = 0; l < LNUM; ++l) {
        int nx[16];
        for (int j = 0; j < 16; ++j) nx[j] = cur[perms[l * 16 + j]];
        for (int j = 0; j < 16; ++j) { c[(l + 1) * 16 + j] = nx[j]; cur[j] = nx[j]; }
    }
}

// float k of a 10-f4 stage buffer (compile-time k)
#define GBX(W, k) (W[(k) / 4][(k) % 4])

// prefetch the 10 f4 of stage SIDX's LDS part into PB
#define PREFL(PB, SIDX)                                                       \
    {                                                                         \
        const f4* sp = &wlds[(SIDX) * 10];                                    \
        _Pragma("unroll") for (int j = 0; j < 10; ++j) PB[j] = sp[j];         \
        __builtin_amdgcn_sched_barrier(0);                                    \
    }

// one 8x8 stage, dual-sourced: bias+rows0-2 from SMEM (uniform -> s_load,
// SGPR operand broadcast), rows3-7 from the LDS-prefetched buffer CB.
// Accumulation order identical to r13: bias, +row0, ..., +row7.
#define STGH(IN, OUT, DOLR, PB, PIDX, CB, WS)                                 \
    {                                                                         \
        PREFL(PB, PIDX)                                                       \
        _Pragma("unroll") for (int o = 0; o < 8; ++o) {                       \
            const float bb = (WS)[o], w0 = (WS)[8 + o];                       \
            _Pragma("unroll") for (int s = 0; s < 2; ++s)                     \
                OUT[s][o] = fmaf(IN[s][0], w0, bb);                           \
        }                                                                     \
        _Pragma("unroll") for (int i2 = 1; i2 < 3; ++i2)                      \
            _Pragma("unroll") for (int o = 0; o < 8; ++o) {                   \
                const float w = (WS)[8 + i2 * 8 + o];                         \
                _Pragma("unroll") for (int s = 0; s < 2; ++s)                 \
                    OUT[s][o] = fmaf(IN[s][i2], w, OUT[s][o]);                \
            }                                                                 \
        _Pragma("unroll") for (int rr = 0; rr < 5; ++rr)                      \
            _Pragma("unroll") for (int o = 0; o < 8; ++o) {                   \
                const float w = GBX(CB, rr * 8 + o);                          \
                _Pragma("unroll") for (int s = 0; s < 2; ++s)                 \
                    OUT[s][o] = fmaf(IN[s][3 + rr], w, OUT[s][o]);            \
            }                                                                 \
        if (DOLR) {                                                           \
            _Pragma("unroll") for (int s = 0; s < 2; ++s)                     \
                _Pragma("unroll") for (int o = 0; o < 8; ++o)                 \
                    OUT[s][o] = fmaxf(OUT[s][o], 0.01f * OUT[s][o]);          \
        }                                                                     \
    }

// S=2, 512 thr, 8 waves/CU. Every stage splits its weight stream across the
// LDS pipe (rows3-7, 100 b128/layer/wave vs r13's 180) and the scalar pipe
// (bias+rows0-2, s_load + SGPR-operand broadcast). LDS-resident x.
extern "C" __global__ void __launch_bounds__(512) flow_fwd(
    const float* __restrict__ z, const float* __restrict__ ws,
    const int* __restrict__ cperm,
    float* __restrict__ outy, float* __restrict__ outld) {
    __shared__ f4 wlds[NL4];          // 24.2 KB LDS weight slab (rows 3-7)
    __shared__ float xs[512 * 33];    // 67.6 KB per-thread {A:0..15, B:16..31, pad}
    const int t = threadIdx.x;
    const long i = (long)blockIdx.x * 512 + t;
    float* __restrict__ myx = &xs[t * 33];
    const float* __restrict__ gsm = ws + NLF;   // SMEM weight region base

    {   // one-time block-cooperative LDS-slab copy
        const f4* gs = reinterpret_cast<const f4*>(ws);
        for (int k = t; k < NL4; k += 512) wlds[k] = gs[k];
    }
    {   // load z into the LDS-resident x slots
        const float4* zp = reinterpret_cast<const float4*>(z + i * 16);
        const float4* zq = reinterpret_cast<const float4*>(z + (i + HALF) * 16);
#pragma unroll
        for (int q = 0; q < 4; ++q) {
            float4 a = zp[q], b = zq[q];
            myx[4 * q] = a.x; myx[4 * q + 1] = a.y; myx[4 * q + 2] = a.z; myx[4 * q + 3] = a.w;
            myx[16 + 4 * q] = b.x; myx[17 + 4 * q] = b.y; myx[18 + 4 * q] = b.z; myx[19 + 4 * q] = b.w;
        }
    }
    float ld2A = 0.f, ld2B = 0.f;
    __syncthreads();

    f4 WA[10], WB[10];
    PREFL(WA, 0)

#pragma unroll 1
    for (int l = 0; l < LNUM; ++l) {
        const int* __restrict__ cl = cperm + l * 16;        // block-uniform -> s_load
        const float* __restrict__ wsm = gsm + l * 320;      // 10 stages x 32 floats
        const int base = l * 10;
        float in2[2][8];
#pragma unroll
        for (int j = 0; j < 8; ++j) {   // gather z_l once, reused by both nets
            const int off = cl[j];
            in2[0][j] = myx[off];
            in2[1][j] = myx[16 + off];
        }
        float h[2][8], g[2][8], sf[2][8], bf[2][8];
        // net 0: log_s (log2 domain)
        STGH(in2, h, 1, WB, base + 1, WA, wsm + 0)
        STGH(h, g, 1,   WA, base + 2, WB, wsm + 32)
        STGH(g, h, 1,   WB, base + 3, WA, wsm + 64)
        STGH(h, g, 1,   WA, base + 4, WB, wsm + 96)
        STGH(g, sf, 0,  WB, base + 5, WA, wsm + 128)
        // net 1: b
        STGH(in2, h, 1, WA, base + 6, WB, wsm + 160)
        STGH(h, g, 1,   WB, base + 7, WA, wsm + 192)
        STGH(g, h, 1,   WA, base + 8, WB, wsm + 224)
        STGH(h, g, 1,   WB, base + 9, WA, wsm + 256)
        STGH(g, bf, 0,  WA, base + 10, WB, wsm + 288)   // prefetch next layer stage 0

#pragma unroll
        for (int k = 0; k < 8; ++k) {
            const int off = cl[8 + k];
            const float cA = fminf(fmaxf(sf[0][k], -L2CLIP), L2CLIP);
            const float cB = fminf(fmaxf(sf[1][k], -L2CLIP), L2CLIP);
            ld2A += cA; ld2B += cB;
            myx[off]      = fmaf(__builtin_amdgcn_exp2f(cA) + 1e-6f, myx[off],      bf[0][k]);
            myx[16 + off] = fmaf(__builtin_amdgcn_exp2f(cB) + 1e-6f, myx[16 + off], bf[1][k]);
        }
    }

    {   // final gather through c[15] and store
        const int* __restrict__ cf = cperm + LNUM * 16;
        float4 oa[4], ob[4];
#pragma unroll
        for (int q = 0; q < 4; ++q) {
            const int c0 = cf[4 * q], c1 = cf[4 * q + 1], c2 = cf[4 * q + 2], c3 = cf[4 * q + 3];
            oa[q].x = myx[c0]; oa[q].y = myx[c1]; oa[q].z = myx[c2]; oa[q].w = myx[c3];
            ob[q].x = myx[16 + c0]; ob[q].y = myx[16 + c1];
            ob[q].z = myx[16 + c2]; ob[q].w = myx[16 + c3];
        }
        float4* ya = reinterpret_cast<float4*>(outy + i * 16);
        float4* yb = reinterpret_cast<float4*>(outy + (i + HALF) * 16);
#pragma unroll
        for (int q = 0; q < 4; ++q) { ya[q] = oa[q]; yb[q] = ob[q]; }
        outld[i] = ld2A * LN2;
        outld[i + HALF] = ld2B * LN2;
    }
}

extern "C" void kernel_launch(void* const* d_in, const int* in_sizes, int n_in,
                              void* d_out, int out_size, void* d_ws, size_t ws_size,
                              hipStream_t stream) {
    const float* z = (const float*)d_in[0];
    const float* Wi = (const float*)d_in[1];
    const float* bi = (const float*)d_in[2];
    const float* Wh = (const float*)d_in[3];
    const float* bh = (const float*)d_in[4];
    const float* Wo = (const float*)d_in[5];
    const float* bo = (const float*)d_in[6];
    const int* perms = (const int*)d_in[7];
    float* out = (float*)d_out;
    float* ws = (float*)d_ws;                      // [LDS part NLF][SMEM part NSF]
    int* cperm = (int*)(ws + NLF + NSF);           // (LNUM+1)*16 ints

    hipLaunchKernelGGL(build_slab, dim3((NLF + NSF + 255) / 256), dim3(256), 0, stream,
                       Wi, bi, Wh, bh, Wo, bo, ws);
    hipLaunchKernelGGL(compose_perms, dim3(1), dim3(64), 0, stream, perms, cperm);
    hipLaunchKernelGGL(flow_fwd, dim3(HALF / 512), dim3(512), 0, stream,
                       z, ws, cperm, out, out + (size_t)BN * 16);
}

// Round 21
// 96.830 us; speedup vs baseline: 1.4430x; 1.4430x over previous
//
#include <hip/hip_runtime.h>

#define BN 262144
#define HALF (BN / 2)
#define LNUM 15
// slab: 151 stages x 72 floats, per stage: [bias 8][W 64 row-major]; stage 150 = dup of 0
#define NSTG 151
#define NF4 (NSTG * 18)
#define LOG2E 1.4426950408889634f
#define LN2 0.6931471805599453f
#define L2CLIP 7.2134752044448170f   // 5*log2e

extern "C" __global__ void build_slab(
    const float* __restrict__ Wi, const float* __restrict__ bi,
    const float* __restrict__ Wh, const float* __restrict__ bh,
    const float* __restrict__ Wo, const float* __restrict__ bo,
    float* __restrict__ slab) {
    int idx = blockIdx.x * 256 + threadIdx.x;
    if (idx >= NSTG * 72) return;
    int sl = idx / 72, k = idx % 72;
    if (sl == NSTG - 1) sl = 0;
    const int l = sl / 10, r = sl % 10, net = r / 5, st = r % 5;
    const int nb = l * 2 + net;
    // net0 stage4 produces log_s: pre-scale by log2e so kernel uses exp2
    const float sc = (net == 0 && st == 4) ? LOG2E : 1.0f;
    float v;
    if (k < 8) {
        if (st == 0)      v = bi[nb * 8 + k];
        else if (st < 4)  v = bh[(nb * 3 + (st - 1)) * 8 + k];
        else              v = bo[nb * 8 + k] * sc;
    } else {
        const int kk = k - 8;
        if (st == 0)      v = Wi[nb * 64 + kk];
        else if (st < 4)  v = Wh[(nb * 3 + (st - 1)) * 64 + kk];
        else              v = Wo[nb * 64 + kk] * sc;
    }
    slab[idx] = v;
}

// cumulative maps: logical x[j] at layer l lives at physical slot c[l][j]
extern "C" __global__ void compose_perms(const int* __restrict__ perms, int* __restrict__ c) {
    if (threadIdx.x != 0 || blockIdx.x != 0) return;
    int cur[16];
    for (int j = 0; j < 16; ++j) { cur[j] = j; c[j] = j; }
    for (int l = 0; l < LNUM; ++l) {
        int nx[16];
        for (int j = 0; j < 16; ++j) nx[j] = cur[perms[l * 16 + j]];
        for (int j = 0; j < 16; ++j) { c[(l + 1) * 16 + j] = nx[j]; cur[j] = nx[j]; }
    }
}

// float k of a 6-float4 group buffer (compile-time k)
#define GB(gb, k) ((k) % 4 == 0 ? gb[(k) / 4].x : (k) % 4 == 1 ? gb[(k) / 4].y \
                 : (k) % 4 == 2 ? gb[(k) / 4].z : gb[(k) / 4].w)

// chunk A: bias + rows 0,1 from BUF; refill BUF with group 3 ahead; fence
#define CHA(IN, OUT, BUF)                                                     \
    {                                                                         \
        _Pragma("unroll") for (int o = 0; o < 8; ++o) {                       \
            const float bb = GB(BUF, o);                                      \
            const float w0 = GB(BUF, 8 + o), w1 = GB(BUF, 16 + o);            \
            _Pragma("unroll") for (int s = 0; s < 2; ++s)                     \
                OUT[s][o] = fmaf(IN[s][1], w1, fmaf(IN[s][0], w0, bb));       \
        }                                                                     \
        _Pragma("unroll") for (int j = 0; j < 6; ++j) BUF[j] = gptr[j];       \
        gptr += 6;                                                            \
        __builtin_amdgcn_sched_barrier(0);                                    \
    }
#define CHB(IN, OUT, BUF)                                                     \
    {                                                                         \
        _Pragma("unroll") for (int o = 0; o < 8; ++o) {                       \
            const float w2 = GB(BUF, o), w3 = GB(BUF, 8 + o), w4 = GB(BUF, 16 + o); \
            _Pragma("unroll") for (int s = 0; s < 2; ++s)                     \
                OUT[s][o] = fmaf(IN[s][4], w4,                                 \
                             fmaf(IN[s][3], w3, fmaf(IN[s][2], w2, OUT[s][o]))); \
        }                                                                     \
        _Pragma("unroll") for (int j = 0; j < 6; ++j) BUF[j] = gptr[j];       \
        gptr += 6;                                                            \
        __builtin_amdgcn_sched_barrier(0);                                    \
    }
#define CHC(IN, OUT, BUF, DOLR)                                               \
    {                                                                         \
        _Pragma("unroll") for (int o = 0; o < 8; ++o) {                       \
            const float w5 = GB(BUF, o), w6 = GB(BUF, 8 + o), w7 = GB(BUF, 16 + o); \
            _Pragma("unroll") for (int s = 0; s < 2; ++s) {                   \
                float a = fmaf(IN[s][7], w7,                                   \
                            fmaf(IN[s][6], w6, fmaf(IN[s][5], w5, OUT[s][o]))); \
                OUT[s][o] = (DOLR) ? fmaxf(a, 0.01f * a) : a;                 \
            }                                                                 \
        }                                                                     \
        _Pragma("unroll") for (int j = 0; j < 6; ++j) BUF[j] = gptr[j];       \
        gptr += 6;                                                            \
        __builtin_amdgcn_sched_barrier(0);                                    \
    }
// one 8x8 stage = 3 chunks rotating through B0,B1,B2
#define STG(IN, OUT, DOLR) CHA(IN, OUT, B0) CHB(IN, OUT, B1) CHC(IN, OUT, B2, DOLR)

// S=2 samples/thread, 8 waves/CU. x LDS-resident (composed perms index it);
// weights stream LDS->3 rotating VGPR group buffers, pinned by sched_barrier.
extern "C" __global__ void __launch_bounds__(512) flow_fwd(
    const float* __restrict__ z, const float* __restrict__ slab,
    const int* __restrict__ cperm,
    float* __restrict__ outy, float* __restrict__ outld) {
    __shared__ float4 wls[NF4];       // 43.5 KB
    __shared__ float xs[512 * 33];    // 67.6 KB: per-thread {A:0..15, B:16..31, pad}
    const int t = threadIdx.x;
    const long i = (long)blockIdx.x * 512 + t;
    float* __restrict__ myx = &xs[t * 33];

    {   // one-time block-cooperative slab copy
        const float4* gs = reinterpret_cast<const float4*>(slab);
        for (int k = t; k < NF4; k += 512) wls[k] = gs[k];
    }
    {   // load z into the LDS-resident x slots
        const float4* zp = reinterpret_cast<const float4*>(z + i * 16);
        const float4* zq = reinterpret_cast<const float4*>(z + (i + HALF) * 16);
#pragma unroll
        for (int q = 0; q < 4; ++q) {
            float4 a = zp[q], b = zq[q];
            myx[4 * q] = a.x; myx[4 * q + 1] = a.y; myx[4 * q + 2] = a.z; myx[4 * q + 3] = a.w;
            myx[16 + 4 * q] = b.x; myx[17 + 4 * q] = b.y; myx[18 + 4 * q] = b.z; myx[19 + 4 * q] = b.w;
        }
    }
    float ld2A = 0.f, ld2B = 0.f;
    __syncthreads();

    float4 B0[6], B1[6], B2[6];
#pragma unroll
    for (int j = 0; j < 6; ++j) { B0[j] = wls[j]; B1[j] = wls[6 + j]; B2[j] = wls[12 + j]; }
    const float4* gptr = wls + 18;
    __builtin_amdgcn_sched_barrier(0);

#pragma unroll 1
    for (int l = 0; l < LNUM; ++l) {
        const int* __restrict__ cl = cperm + l * 16;   // block-uniform -> s_load
        float in2[2][8];
#pragma unroll
        for (int j = 0; j < 8; ++j) {   // gather z_l once, reused by both nets
            const int off = cl[j];
            in2[0][j] = myx[off];
            in2[1][j] = myx[16 + off];
        }
        float h[2][8], g[2][8], sf[2][8], bf[2][8];
        // net 0: log_s (log2 domain)
        STG(in2, h, 1) STG(h, g, 1) STG(g, h, 1) STG(h, g, 1) STG(g, sf, 0)
        // net 1: b
        STG(in2, h, 1) STG(h, g, 1) STG(g, h, 1) STG(h, g, 1) STG(g, bf, 0)

#pragma unroll
        for (int k = 0; k < 8; ++k) {
            const int off = cl[8 + k];
            const float cA = fminf(fmaxf(sf[0][k], -L2CLIP), L2CLIP);
            const float cB = fminf(fmaxf(sf[1][k], -L2CLIP), L2CLIP);
            ld2A += cA; ld2B += cB;
            myx[off]      = fmaf(__builtin_amdgcn_exp2f(cA) + 1e-6f, myx[off],      bf[0][k]);
            myx[16 + off] = fmaf(__builtin_amdgcn_exp2f(cB) + 1e-6f, myx[16 + off], bf[1][k]);
        }
    }

    {   // final gather through c[15] and store
        const int* __restrict__ cf = cperm + LNUM * 16;
        float4 oa[4], ob[4];
#pragma unroll
        for (int q = 0; q < 4; ++q) {
            const int c0 = cf[4 * q], c1 = cf[4 * q + 1], c2 = cf[4 * q + 2], c3 = cf[4 * q + 3];
            oa[q].x = myx[c0]; oa[q].y = myx[c1]; oa[q].z = myx[c2]; oa[q].w = myx[c3];
            ob[q].x = myx[16 + c0]; ob[q].y = myx[16 + c1];
            ob[q].z = myx[16 + c2]; ob[q].w = myx[16 + c3];
        }
        float4* ya = reinterpret_cast<float4*>(outy + i * 16);
        float4* yb = reinterpret_cast<float4*>(outy + (i + HALF) * 16);
#pragma unroll
        for (int q = 0; q < 4; ++q) { ya[q] = oa[q]; yb[q] = ob[q]; }
        outld[i] = ld2A * LN2;
        outld[i + HALF] = ld2B * LN2;
    }
}

extern "C" void kernel_launch(void* const* d_in, const int* in_sizes, int n_in,
                              void* d_out, int out_size, void* d_ws, size_t ws_size,
                              hipStream_t stream) {
    const float* z = (const float*)d_in[0];
    const float* Wi = (const float*)d_in[1];
    const float* bi = (const float*)d_in[2];
    const float* Wh = (const float*)d_in[3];
    const float* bh = (const float*)d_in[4];
    const float* Wo = (const float*)d_in[5];
    const float* bo = (const float*)d_in[6];
    const int* perms = (const int*)d_in[7];
    float* out = (float*)d_out;
    float* slab = (float*)d_ws;                    // NSTG*72 floats
    int* cperm = (int*)(slab + NSTG * 72);         // (LNUM+1)*16 ints

    hipLaunchKernelGGL(build_slab, dim3((NSTG * 72 + 255) / 256), dim3(256), 0, stream,
                       Wi, bi, Wh, bh, Wo, bo, slab);
    hipLaunchKernelGGL(compose_perms, dim3(1), dim3(64), 0, stream, perms, cperm);
    hipLaunchKernelGGL(flow_fwd, dim3(HALF / 512), dim3(512), 0, stream,
                       z, slab, cperm, out, out + (size_t)BN * 16);
}